// Round 6
// baseline (2944.726 us; speedup 1.0000x reference)
//
#include <hip/hip_runtime.h>
#include <hip/hip_bf16.h>
#include <math.h>

constexpr int NN  = 100000;   // nodes
constexpr int EE  = 3200000;  // edges
constexpr int HID = 128;
constexpr int NG  = 512;      // 4*HID
constexpr int NOUT = 64;
constexpr int HOPS = 10;
constexpr int SCAN_BLK = 1024;
constexpr int NBLK_SCAN = (NN + SCAN_BLK - 1) / SCAN_BLK;   // 98
constexpr int NB = (NN + 255) / 256;                        // 391 row-buckets (256 rows each)
constexpr int PA_BATCH = 4096;                              // edges per pass-A block
constexpr int PA_GRID = (EE + PA_BATCH - 1) / PA_BATCH;     // 782

typedef __attribute__((ext_vector_type(8))) short short8;
typedef __attribute__((ext_vector_type(4))) float f32x4;

__device__ __forceinline__ ushort f2bf(float f) {
    uint u = __builtin_bit_cast(uint, f);
    u += 0x7fff + ((u >> 16) & 1);          // RNE
    return (ushort)(u >> 16);
}
__device__ __forceinline__ float bflo(uint u) { return __builtin_bit_cast(float, u << 16); }
__device__ __forceinline__ float bfhi(uint u) { return __builtin_bit_cast(float, u & 0xffff0000u); }

__device__ __forceinline__ float sigf(float v) { return 1.0f / (1.0f + __expf(-v)); }
__device__ __forceinline__ float tanh_fast(float x) {
    float t = __expf(-2.0f * fabsf(x));
    float r = (1.0f - t) / (1.0f + t);
    return copysignf(r, x);
}

__device__ __forceinline__ short8 load_frag(const ushort* p) {
    return *reinterpret_cast<const short8*>(p);
}
__device__ __forceinline__ f32x4 mfma16(short8 a, short8 b, f32x4 c) {
    return __builtin_amdgcn_mfma_f32_16x16x32_bf16(a, b, c, 0, 0, 0);
}

// ---------------------------------------------------------------------------
// fp32 -> bf16 conversion (vectorized), n4 = n/4
// ---------------------------------------------------------------------------
__global__ __launch_bounds__(256) void convert_bf16_kernel(
    const float* __restrict__ src, ushort* __restrict__ dst, int n4)
{
    int i = blockIdx.x * 256 + threadIdx.x;
    if (i < n4) {
        float4 v = reinterpret_cast<const float4*>(src)[i];
        ushort4 o;
        o.x = f2bf(v.x); o.y = f2bf(v.y); o.z = f2bf(v.z); o.w = f2bf(v.w);
        reinterpret_cast<ushort4*>(dst)[i] = o;
    }
}

__global__ __launch_bounds__(256) void bsum_kernel(
    const float* __restrict__ bih, const float* __restrict__ bhh, float* __restrict__ bsum)
{
    int i = blockIdx.x * 256 + threadIdx.x;
    if (i < NG) bsum[i] = bih[i] + bhh[i];
}

// ---------------------------------------------------------------------------
// CSR build: histogram -> 3-stage scan -> bucketed 2-pass scatter
// ---------------------------------------------------------------------------
__global__ __launch_bounds__(256) void hist_kernel(const int* __restrict__ erow,
                                                   int* __restrict__ deg)
{
    int e = blockIdx.x * 256 + threadIdx.x;
    atomicAdd(&deg[erow[e]], 1);
}

// stage 1: per-block (1024 elems) sum -> bsums
__global__ __launch_bounds__(SCAN_BLK) void scan1_kernel(const int* __restrict__ deg,
                                                         int* __restrict__ bsums)
{
    __shared__ int tmp[SCAN_BLK];
    int t = threadIdx.x;
    int i = blockIdx.x * SCAN_BLK + t;
    tmp[t] = (i < NN) ? deg[i] : 0;
    __syncthreads();
    for (int off = SCAN_BLK / 2; off > 0; off >>= 1) {
        if (t < off) tmp[t] += tmp[t + off];
        __syncthreads();
    }
    if (t == 0) bsums[blockIdx.x] = tmp[0];
}

// stage 2: exclusive scan of bsums (NBLK_SCAN <= 128), single block
__global__ __launch_bounds__(128) void scan2_kernel(int* __restrict__ bsums)
{
    __shared__ int tmp[128];
    int t = threadIdx.x;
    tmp[t] = (t < NBLK_SCAN) ? bsums[t] : 0;
    __syncthreads();
    for (int off = 1; off < 128; off <<= 1) {
        int add = (t >= off) ? tmp[t - off] : 0;
        __syncthreads();
        tmp[t] += add;
        __syncthreads();
    }
    if (t < NBLK_SCAN) bsums[t] = (t == 0) ? 0 : tmp[t - 1];
}

// stage 3: per-block inclusive scan + block offset -> rp, cur
__global__ __launch_bounds__(SCAN_BLK) void scan3_kernel(const int* __restrict__ deg,
                                                         const int* __restrict__ bsums,
                                                         int* __restrict__ rp,
                                                         int* __restrict__ cur)
{
    __shared__ int tmp[SCAN_BLK];
    int t = threadIdx.x;
    int i = blockIdx.x * SCAN_BLK + t;
    int v = (i < NN) ? deg[i] : 0;
    tmp[t] = v;
    __syncthreads();
    for (int off = 1; off < SCAN_BLK; off <<= 1) {
        int add = (t >= off) ? tmp[t - off] : 0;
        __syncthreads();
        tmp[t] += add;
        __syncthreads();
    }
    int incl = tmp[t] + bsums[blockIdx.x];
    if (i < NN) {
        rp[i + 1] = incl;
        cur[i] = incl - v;
    }
    if (i == 0) rp[0] = 0;
}

// bucket cursors: bucket b (rows 256b..256b+255) starts at rp[256*b]
__global__ __launch_bounds__(512) void binit_kernel(const int* __restrict__ rp,
                                                    int* __restrict__ bcur)
{
    int b = threadIdx.x;
    if (b < NB) bcur[b] = rp[b << 8];
}

// pass A: partition edges into 391 row-buckets (block-local LDS binning)
__global__ __launch_bounds__(256) void passA_kernel(
    const int* __restrict__ erow, const int* __restrict__ ecol,
    const float* __restrict__ eval, int* __restrict__ bcur,
    int* __restrict__ trow, int2* __restrict__ tcv)
{
    __shared__ int  lhist[512];
    __shared__ int  sa[512];
    __shared__ int  sb[512];
    __shared__ int  gbase[512];
    __shared__ int  srow[PA_BATCH];
    __shared__ int2 scv[PA_BATCH];

    const int t = threadIdx.x;
    const int base = blockIdx.x * PA_BATCH;
    const int nb = min(PA_BATCH, EE - base);

    lhist[t] = 0; lhist[t + 256] = 0;
    __syncthreads();

    // bin: count per bucket, remember (bucket,pos) per edge
    int er[16], ec[16], pk[16];
    float ev[16];
#pragma unroll
    for (int k = 0; k < 16; ++k) {
        int idx = k * 256 + t;
        if (idx < nb) {
            int e = base + idx;
            int r = erow[e];
            er[k] = r; ec[k] = ecol[e]; ev[k] = eval[e];
            int b = r >> 8;
            int pos = atomicAdd(&lhist[b], 1);
            pk[k] = b | (pos << 9);
        } else pk[k] = -1;
    }
    __syncthreads();

    // inclusive scan of lhist[0..511] -> incl (ping-pong sa/sb)
    sa[t] = lhist[t]; sa[t + 256] = lhist[t + 256];
    __syncthreads();
    int* src = sa; int* dst = sb;
    for (int off = 1; off < 512; off <<= 1) {
        dst[t] = src[t] + ((t >= off) ? src[t - off] : 0);
        int i2 = t + 256;
        dst[i2] = src[i2] + src[i2 - off];
        __syncthreads();
        int* tp = src; src = dst; dst = tp;
    }
    int* incl = src;   // 9 iterations -> result in src

    // reserve global bucket space
    for (int b = t; b < NB; b += 256) {
        int cnt = lhist[b];
        gbase[b] = cnt ? atomicAdd(&bcur[b], cnt) : 0;
    }
    __syncthreads();

    // stage into bucket-sorted LDS order
#pragma unroll
    for (int k = 0; k < 16; ++k) {
        if (pk[k] >= 0) {
            int b = pk[k] & 511;
            int pos = pk[k] >> 9;
            int lofs = b ? incl[b - 1] : 0;
            int s = lofs + pos;
            srow[s] = er[k];
            scv[s] = int2{ec[k], __builtin_bit_cast(int, ev[k])};
        }
    }
    __syncthreads();

    // flush: bucket-runs -> contiguous global ranges
    for (int s = t; s < nb; s += 256) {
        int rr = srow[s];
        int b = rr >> 8;
        int lofs = b ? incl[b - 1] : 0;
        int g = gbase[b] + (s - lofs);
        trow[g] = rr;
        tcv[g] = scv[s];
    }
}

// pass B: exact scatter within L2-resident bucket windows
__global__ __launch_bounds__(256) void passB_kernel(
    const int* __restrict__ trow, const int2* __restrict__ tcv,
    int* __restrict__ cur, int2* __restrict__ epack)
{
    int e = blockIdx.x * 256 + threadIdx.x;
    int r = trow[e];
    int2 cv = tcv[e];
    int p = atomicAdd(&cur[r], 1);
    epack[p] = cv;
}

// ---------------------------------------------------------------------------
// Fused LSTM cell, wave-specialized gates.
// Block = 32 rows (NN = 3125*32 exactly), 4 waves.
// Wave w computes gate-row-blocks n = 4*nI + w (nI=0..7): i/f/g/o blocks for
// one hidden col are n, n+8, n+16, n+24 — all congruent mod 4 — so the LSTM
// elementwise is wave-local.
// c is stored in a per-thread permuted layout (private to this kernel).
// h is transposed via LDS to standard [row][col] bf16 for the SpMM gather.
// ---------------------------------------------------------------------------
template<bool FIRST>
__global__ __launch_bounds__(256, 2) void cell_kernel(
    const ushort* __restrict__ xb, const ushort* __restrict__ hb,
    const ushort* __restrict__ Wib, const ushort* __restrict__ Whb,
    const float* __restrict__ bsum, float* __restrict__ cperm,
    ushort* __restrict__ hout)
{
    __shared__ __align__(16) ushort lds_h[32 * 136];

    const int t  = threadIdx.x;
    const int l  = t & 63;
    const int w  = t >> 6;
    const int lr = l & 15;
    const int lk = l >> 4;
    const int row0 = blockIdx.x * 32;

    // accumulators: acc[nI][rf] -> gate-col (4*nI+w)*16+lr, rows rf*16+lk*4+jj
    f32x4 acc[8][2];
#pragma unroll
    for (int nI = 0; nI < 8; ++nI) {
        float b = bsum[(4 * nI + w) * 16 + lr];
        acc[nI][0] = f32x4{b, b, b, b};
        acc[nI][1] = f32x4{b, b, b, b};
    }

    // preload A fragments (x and h), 16B each
    short8 ax[2][4];
    short8 ah[2][4];
#pragma unroll
    for (int rf = 0; rf < 2; ++rf) {
        const size_t arow = (size_t)(row0 + rf * 16 + lr) * HID + lk * 8;
#pragma unroll
        for (int ks = 0; ks < 4; ++ks) {
            ax[rf][ks] = load_frag(xb + arow + ks * 32);
            if (!FIRST) ah[rf][ks] = load_frag(hb + arow + ks * 32);
        }
    }

#pragma unroll
    for (int nI = 0; nI < 8; ++nI) {
        const int n = 4 * nI + w;
        const ushort* wip = Wib + (size_t)(n * 16 + lr) * HID + lk * 8;
        const ushort* whp = Whb + (size_t)(n * 16 + lr) * HID + lk * 8;
        short8 bi[4], bh[4];
#pragma unroll
        for (int ks = 0; ks < 4; ++ks) {
            bi[ks] = load_frag(wip + ks * 32);
            if (!FIRST) bh[ks] = load_frag(whp + ks * 32);
        }
#pragma unroll
        for (int rf = 0; rf < 2; ++rf) {
#pragma unroll
            for (int ks = 0; ks < 4; ++ks) {
                acc[nI][rf] = mfma16(ax[rf][ks], bi[ks], acc[nI][rf]);
                if (!FIRST) acc[nI][rf] = mfma16(ah[rf][ks], bh[ks], acc[nI][rf]);
            }
        }
    }

    // epilogue: LSTM elementwise; c in permuted layout, h via LDS transpose
#pragma unroll
    for (int nj = 0; nj < 2; ++nj) {
        const int col = (w + 4 * nj) * 16 + lr;
#pragma unroll
        for (int rf = 0; rf < 2; ++rf) {
            f32x4 iv = acc[nj][rf];
            f32x4 fv = acc[nj + 2][rf];
            f32x4 gv = acc[nj + 4][rf];
            f32x4 ov = acc[nj + 6][rf];
            const size_t cidx = ((((size_t)blockIdx.x * 4 + w) * 2 + nj) * 2 + rf) * 64 + l;
            f32x4 cold;
            if (FIRST) cold = f32x4{0.f, 0.f, 0.f, 0.f};
            else       cold = reinterpret_cast<const f32x4*>(cperm)[cidx];
            f32x4 cn, hn;
#pragma unroll
            for (int jj = 0; jj < 4; ++jj) {
                float c2 = sigf(fv[jj]) * cold[jj] + sigf(iv[jj]) * tanh_fast(gv[jj]);
                cn[jj] = c2;
                hn[jj] = sigf(ov[jj]) * tanh_fast(c2);
            }
            reinterpret_cast<f32x4*>(cperm)[cidx] = cn;
            const int rbase = rf * 16 + lk * 4;
#pragma unroll
            for (int jj = 0; jj < 4; ++jj)
                lds_h[(rbase + jj) * 136 + col] = f2bf(hn[jj]);
        }
    }
    __syncthreads();
    // coalesced h store: thread t moves 16 ushorts: tile row t>>3, cols (t&7)*16..+15
    {
        const ushort* lsrc = &lds_h[(t >> 3) * 136 + (t & 7) * 16];
        short8 v0 = *reinterpret_cast<const short8*>(lsrc);
        short8 v1 = *reinterpret_cast<const short8*>(lsrc + 8);
        ushort* gdst = hout + (size_t)row0 * HID + t * 16;
        *reinterpret_cast<short8*>(gdst) = v0;
        *reinterpret_cast<short8*>(gdst + 8) = v1;
    }
}

// ---------------------------------------------------------------------------
// SpMM: hout[r,:] = sum_e val[e] * hin[col[e],:]   (bf16 in/out, fp32 accum)
// one wave per row, lane owns 2 features (dword); packed (col,val) stream
// read nontemporally to preserve L2 for the h gather working set
// ---------------------------------------------------------------------------
__global__ __launch_bounds__(256) void spmm_kernel(
    const int* __restrict__ rp, const int2* __restrict__ epack,
    const ushort* __restrict__ hin, ushort* __restrict__ hout)
{
    int r = blockIdx.x * 4 + (threadIdx.x >> 6);
    if (r >= NN) return;
    int l = threadIdx.x & 63;
    int beg = rp[r], end = rp[r + 1];
    const unsigned long long* eq = reinterpret_cast<const unsigned long long*>(epack);

    float s0a = 0.f, s1a = 0.f, s0b = 0.f, s1b = 0.f;
    float s0c = 0.f, s1c = 0.f, s0d = 0.f, s1d = 0.f;
    int e = beg;
    for (; e + 4 <= end; e += 4) {
        unsigned long long u0 = __builtin_nontemporal_load(eq + e);
        unsigned long long u1 = __builtin_nontemporal_load(eq + e + 1);
        unsigned long long u2 = __builtin_nontemporal_load(eq + e + 2);
        unsigned long long u3 = __builtin_nontemporal_load(eq + e + 3);
        int c0 = (int)(uint)u0, c1 = (int)(uint)u1, c2 = (int)(uint)u2, c3 = (int)(uint)u3;
        float v0 = __builtin_bit_cast(float, (uint)(u0 >> 32));
        float v1 = __builtin_bit_cast(float, (uint)(u1 >> 32));
        float v2 = __builtin_bit_cast(float, (uint)(u2 >> 32));
        float v3 = __builtin_bit_cast(float, (uint)(u3 >> 32));
        uint g0 = *reinterpret_cast<const uint*>(hin + (size_t)c0 * HID + l * 2);
        uint g1 = *reinterpret_cast<const uint*>(hin + (size_t)c1 * HID + l * 2);
        uint g2 = *reinterpret_cast<const uint*>(hin + (size_t)c2 * HID + l * 2);
        uint g3 = *reinterpret_cast<const uint*>(hin + (size_t)c3 * HID + l * 2);
        s0a += v0 * bflo(g0); s1a += v0 * bfhi(g0);
        s0b += v1 * bflo(g1); s1b += v1 * bfhi(g1);
        s0c += v2 * bflo(g2); s1c += v2 * bfhi(g2);
        s0d += v3 * bflo(g3); s1d += v3 * bfhi(g3);
    }
    for (; e < end; ++e) {
        unsigned long long u0 = __builtin_nontemporal_load(eq + e);
        int c0 = (int)(uint)u0;
        float v0 = __builtin_bit_cast(float, (uint)(u0 >> 32));
        uint g0 = *reinterpret_cast<const uint*>(hin + (size_t)c0 * HID + l * 2);
        s0a += v0 * bflo(g0); s1a += v0 * bfhi(g0);
    }
    float s0 = (s0a + s0b) + (s0c + s0d);
    float s1 = (s1a + s1b) + (s1c + s1d);
    uint o = ((uint)f2bf(s1) << 16) | (uint)f2bf(s0);
    *reinterpret_cast<uint*>(hout + (size_t)r * HID + l * 2) = o;
}

// ---------------------------------------------------------------------------
// final: out = relu(h) @ fc_w^T + fc_b  (MFMA)
// ---------------------------------------------------------------------------
__global__ __launch_bounds__(256) void final_mfma_kernel(
    const ushort* __restrict__ hb, const ushort* __restrict__ fcwb,
    const float* __restrict__ fcb, float* __restrict__ out)
{
    const int t = threadIdx.x;
    const int l = t & 63;
    const int w = t >> 6;
    const int lr = l & 15;
    const int lk = l >> 4;
    const int row0 = blockIdx.x * 64 + w * 16;

    f32x4 acc[4];
#pragma unroll
    for (int n = 0; n < 4; ++n) {
        float b = fcb[n * 16 + lr];
        acc[n] = f32x4{b, b, b, b};
    }

    const short8 z8 = {0, 0, 0, 0, 0, 0, 0, 0};
    const int arow = row0 + lr;
    const bool aok = arow < NN;
    short8 a[4];
#pragma unroll
    for (int ks = 0; ks < 4; ++ks) {
        short8 v = aok ? load_frag(hb + (size_t)arow * HID + ks * 32 + lk * 8) : z8;
#pragma unroll
        for (int i = 0; i < 8; ++i) {
            ushort u = (ushort)v[i];
            if (u & 0x8000) v[i] = 0;   // relu in bf16
        }
        a[ks] = v;
    }

#pragma unroll
    for (int n = 0; n < 4; ++n) {
        const ushort* wp = fcwb + (size_t)(n * 16 + lr) * HID + lk * 8;
#pragma unroll
        for (int ks = 0; ks < 4; ++ks)
            acc[n] = mfma16(a[ks], load_frag(wp + ks * 32), acc[n]);
    }

#pragma unroll
    for (int n = 0; n < 4; ++n) {
#pragma unroll
        for (int j = 0; j < 4; ++j) {
            int row = row0 + lk * 4 + j;
            if (row < NN) out[(size_t)row * NOUT + n * 16 + lr] = acc[n][j];
        }
    }
}

// ---------------------------------------------------------------------------
extern "C" void kernel_launch(void* const* d_in, const int* in_sizes, int n_in,
                              void* d_out, int out_size, void* d_ws, size_t ws_size,
                              hipStream_t stream)
{
    const float* x    = (const float*)d_in[0];
    const int*   erow = (const int*)d_in[1];
    const int*   ecol = (const int*)d_in[2];
    const float* eval = (const float*)d_in[3];
    const float* Wih  = (const float*)d_in[4];
    const float* Whh  = (const float*)d_in[5];
    const float* bih  = (const float*)d_in[6];
    const float* bhh  = (const float*)d_in[7];
    const float* fcw  = (const float*)d_in[8];
    const float* fcb  = (const float*)d_in[9];
    float* out = (float*)d_out;

    char* ws = (char*)d_ws;
    size_t off = 0;
    auto alloc = [&](size_t bytes) -> void* {
        void* p = ws + off;
        off = (off + bytes + 255) & ~(size_t)255;
        return p;
    };
    ushort* hb_a  = (ushort*)alloc((size_t)NN * HID * 2);
    ushort* hb_b  = (ushort*)alloc((size_t)NN * HID * 2);
    float*  cperm = (float*)alloc((size_t)NN * HID * 4);
    ushort* xb    = (ushort*)alloc((size_t)NN * HID * 2);
    ushort* Wib   = (ushort*)alloc((size_t)NG * HID * 2);
    ushort* Whb   = (ushort*)alloc((size_t)NG * HID * 2);
    ushort* fcwb  = (ushort*)alloc((size_t)NOUT * HID * 2);
    float*  bsum  = (float*)alloc((size_t)NG * 4);
    int*    rp    = (int*)alloc((size_t)(NN + 1) * 4);
    int*    deg   = (int*)alloc((size_t)NN * 4);
    int*    cur   = (int*)alloc((size_t)NN * 4);
    int*    bsums = (int*)alloc((size_t)NBLK_SCAN * 4);
    int*    bcur  = (int*)alloc((size_t)NB * 4);
    int2*   epack = (int2*)alloc((size_t)EE * 8);
    (void)ws_size;

    // temp bucket-grouped edge arrays alias cperm (written only after CSR build)
    int2* tcv  = (int2*)cperm;                               // 25.6 MB
    int*  trow = (int*)((char*)cperm + (size_t)EE * 8);      // 12.8 MB (total 38.4 <= 51.2)

    // conversions to bf16
    convert_bf16_kernel<<<(NN * HID / 4 + 255) / 256, 256, 0, stream>>>(x, xb, NN * HID / 4);
    convert_bf16_kernel<<<(NG * HID / 4 + 255) / 256, 256, 0, stream>>>(Wih, Wib, NG * HID / 4);
    convert_bf16_kernel<<<(NG * HID / 4 + 255) / 256, 256, 0, stream>>>(Whh, Whb, NG * HID / 4);
    convert_bf16_kernel<<<(NOUT * HID / 4 + 255) / 256, 256, 0, stream>>>(fcw, fcwb, NOUT * HID / 4);
    bsum_kernel<<<2, 256, 0, stream>>>(bih, bhh, bsum);

    // CSR build
    hipMemsetAsync(deg, 0, (size_t)NN * 4, stream);
    hist_kernel<<<EE / 256, 256, 0, stream>>>(erow, deg);
    scan1_kernel<<<NBLK_SCAN, SCAN_BLK, 0, stream>>>(deg, bsums);
    scan2_kernel<<<1, 128, 0, stream>>>(bsums);
    scan3_kernel<<<NBLK_SCAN, SCAN_BLK, 0, stream>>>(deg, bsums, rp, cur);
    binit_kernel<<<1, 512, 0, stream>>>(rp, bcur);
    passA_kernel<<<PA_GRID, 256, 0, stream>>>(erow, ecol, eval, bcur, trow, tcv);
    passB_kernel<<<EE / 256, 256, 0, stream>>>(trow, tcv, cur, epack);

    const int CELL_GRID = NN / 32;   // 3125

    cell_kernel<true><<<CELL_GRID, 256, 0, stream>>>(xb, hb_b, Wib, Whb, bsum, cperm, hb_a);
    spmm_kernel<<<(NN + 3) / 4, 256, 0, stream>>>(rp, epack, hb_a, hb_b);
    for (int hop = 1; hop < HOPS; ++hop) {
        cell_kernel<false><<<CELL_GRID, 256, 0, stream>>>(xb, hb_b, Wib, Whb, bsum, cperm, hb_a);
        spmm_kernel<<<(NN + 3) / 4, 256, 0, stream>>>(rp, epack, hb_a, hb_b);
    }

    final_mfma_kernel<<<(NN + 63) / 64, 256, 0, stream>>>(hb_b, fcwb, fcb, out);
}